// Round 1
// baseline (1144.156 us; speedup 1.0000x reference)
//
#include <hip/hip_runtime.h>
#include <stdint.h>

#define NLEV 16
#define LOG2_T 19
#define TMASK ((1u << LOG2_T) - 1u)
#define P1 2654435761u
#define P2 805459861u

__global__ __launch_bounds__(256) void hashenc_kernel(
    const float* __restrict__ x,
    const float* __restrict__ bb,
    const float* __restrict__ table,
    float* __restrict__ enc_out,
    float* __restrict__ mask_out,
    int n)
{
    int i = blockIdx.x * blockDim.x + threadIdx.x;
    if (i >= n) return;

    // bounding box (uniform, L1/L2 cached)
    const float bx0 = bb[0], by0 = bb[1], bz0 = bb[2];
    const float bx1 = bb[3], by1 = bb[4], bz1 = bb[5];

    const float px = x[3 * i + 0];
    const float py = x[3 * i + 1];
    const float pz = x[3 * i + 2];

    // exact fp32 ops to match numpy reference (no rcp/fast-math)
    const float xn = (px - bx0) / (bx1 - bx0);
    const float yn = (py - by0) / (by1 - by0);
    const float zn = (pz - bz0) / (bz1 - bz0);

    const bool inb = (xn > 0.0f) & (xn < 1.0f) &
                     (yn > 0.0f) & (yn < 1.0f) &
                     (zn > 0.0f) & (zn < 1.0f);

    float enc[2 * NLEV];

    for (int l = 0; l < NLEV; ++l) {
        const float res = (float)(16 << l);   // floor(16 * 2^l) exact
        const float posx = xn * res;
        const float posy = yn * res;
        const float posz = zn * res;
        const float flx = floorf(posx);
        const float fly = floorf(posy);
        const float flz = floorf(posz);
        const float fx = posx - flx;
        const float fy = posy - fly;
        const float fz = posz - flz;
        const int ix = (int)flx;
        const int iy = (int)fly;
        const int iz = (int)flz;

        // hash components per axis (wrapping u32 mul; int->uint = two's complement)
        const uint32_t hx0 = (uint32_t)ix;
        const uint32_t hx1 = (uint32_t)(ix + 1);
        const uint32_t hy0 = (uint32_t)iy * P1;
        const uint32_t hy1 = (uint32_t)(iy + 1) * P1;
        const uint32_t hz0 = (uint32_t)iz * P2;
        const uint32_t hz1 = (uint32_t)(iz + 1) * P2;

        const float2* __restrict__ tbl =
            (const float2*)table + ((size_t)l << LOG2_T);

        // corner c: dim0=(c>>2)&1, dim1=(c>>1)&1, dim2=c&1  (matches OFFS)
        uint32_t idx[8];
        idx[0] = (hx0 ^ hy0 ^ hz0) & TMASK;
        idx[1] = (hx0 ^ hy0 ^ hz1) & TMASK;
        idx[2] = (hx0 ^ hy1 ^ hz0) & TMASK;
        idx[3] = (hx0 ^ hy1 ^ hz1) & TMASK;
        idx[4] = (hx1 ^ hy0 ^ hz0) & TMASK;
        idx[5] = (hx1 ^ hy0 ^ hz1) & TMASK;
        idx[6] = (hx1 ^ hy1 ^ hz0) & TMASK;
        idx[7] = (hx1 ^ hy1 ^ hz1) & TMASK;

        float2 f[8];
        #pragma unroll
        for (int c = 0; c < 8; ++c) f[c] = tbl[idx[c]];

        const float gx = 1.0f - fx, gy = 1.0f - fy, gz = 1.0f - fz;
        const float wx[2] = {gx, fx};
        const float wy[2] = {gy, fy};
        const float wz[2] = {gz, fz};

        float s0 = 0.0f, s1 = 0.0f;
        #pragma unroll
        for (int c = 0; c < 8; ++c) {
            const float w = (wx[(c >> 2) & 1] * wy[(c >> 1) & 1]) * wz[c & 1];
            s0 = fmaf(w, f[c].x, s0);
            s1 = fmaf(w, f[c].y, s1);
        }
        enc[2 * l + 0] = s0;
        enc[2 * l + 1] = s1;
    }

    // coalesced-ish vectorized store: each row is 128B-aligned
    float4* o = (float4*)(enc_out + (size_t)i * (2 * NLEV));
    #pragma unroll
    for (int k = 0; k < (2 * NLEV) / 4; ++k)
        o[k] = make_float4(enc[4 * k + 0], enc[4 * k + 1],
                           enc[4 * k + 2], enc[4 * k + 3]);

    mask_out[i] = inb ? 1.0f : 0.0f;
}

extern "C" void kernel_launch(void* const* d_in, const int* in_sizes, int n_in,
                              void* d_out, int out_size, void* d_ws, size_t ws_size,
                              hipStream_t stream) {
    const float* x     = (const float*)d_in[0];
    const float* bb    = (const float*)d_in[1];
    const float* table = (const float*)d_in[2];
    const int n = in_sizes[0] / 3;

    float* enc_out  = (float*)d_out;
    float* mask_out = enc_out + (size_t)n * (2 * NLEV);

    const int block = 256;
    const int grid = (n + block - 1) / block;
    hashenc_kernel<<<grid, block, 0, stream>>>(x, bb, table, enc_out, mask_out, n);
}